// Round 14
// baseline (177.319 us; speedup 1.0000x reference)
//
#include <hip/hip_runtime.h>
#include <math.h>

#define BB 16
#define CC 64
#define NN 2048
#define KK 8
#define CAND 16          // phase-1 candidates (exact top-8 subset; validated R3/R6/R7/R10-R17)
#define QB 8             // query rows per item (one per wave)
#define NT (QB * 64)     // 512 threads
#define MPW (NN / QB)    // 256 m-points per wave
#define TPW (MPW / 32)   // 8 col-tiles of 32 m-points per wave
#define NTILE (NN / 32)  // 64 m-tiles per batch

typedef unsigned long long u64;
typedef unsigned short u16;
typedef __attribute__((ext_vector_type(8)))  short short8;   // 8 bf16 = 4 VGPRs (MFMA A/B frag)
typedef __attribute__((ext_vector_type(16))) float f32x16;   // MFMA 32x32 C/D frag

// order-preserving fp32 -> u32 flip: ascending uint == ascending float
__device__ __forceinline__ unsigned ordflip(float f) {
    unsigned u = __float_as_uint(f);
    return u ^ ((u & 0x80000000u) ? 0xFFFFFFFFu : 0x80000000u);
}
// inverse (on the masked high bits): recover approximate r from a packed key
__device__ __forceinline__ float unflip(unsigned k) {
    unsigned u = k & 0xFFFFF800u;
    u ^= (u & 0x80000000u) ? 0x80000000u : 0xFFFFFFFFu;
    return __uint_as_float(u);
}

__device__ __forceinline__ u16 f2h(float v) {
    union { _Float16 h; u16 u; } c;
    c.h = (_Float16)v;                 // RNE fp32 -> fp16
    return c.u;
}

// ---- cross-lane helpers: DPP for offsets inside a 16-lane row, bpermute beyond ----
template<int C>
__device__ __forceinline__ unsigned dppu(unsigned v) {
    return (unsigned)__builtin_amdgcn_update_dpp(0, (int)v, C, 0xF, 0xF, true);
}
template<int OFF>
__device__ __forceinline__ unsigned shx(unsigned v) {
    if constexpr (OFF == 1)       return dppu<0xB1>(v);    // quad_perm xor 1
    else if constexpr (OFF == 2)  return dppu<0x4E>(v);    // quad_perm xor 2
    else if constexpr (OFF == 7)  return dppu<0x141>(v);   // row_half_mirror = xor 7
    else if constexpr (OFF == 15) return dppu<0x140>(v);   // row_mirror      = xor 15
    else return (unsigned)__shfl_xor((int)v, OFF, 64);
}
template<int C>
__device__ __forceinline__ double dppd(double v) {
    unsigned long long u = (unsigned long long)__double_as_longlong(v);
    int lo = __builtin_amdgcn_update_dpp(0, (int)(u & 0xffffffffull), C, 0xF, 0xF, true);
    int hi = __builtin_amdgcn_update_dpp(0, (int)(u >> 32),           C, 0xF, 0xF, true);
    return __longlong_as_double((long long)(((unsigned long long)(unsigned)hi << 32) | (unsigned)lo));
}

#define CMPX(a_, b_) { unsigned lo_ = (a_) < (b_) ? (a_) : (b_); \
                       unsigned hi_ = (a_) < (b_) ? (b_) : (a_); (a_) = lo_; (b_) = hi_; }

// ascending bitonic cleanup of a bitonic 16-sequence (j = 8,4,2,1)
__device__ __forceinline__ void clean16(unsigned k[CAND]) {
    CMPX(k[0],k[8]) CMPX(k[1],k[9]) CMPX(k[2],k[10]) CMPX(k[3],k[11])
    CMPX(k[4],k[12]) CMPX(k[5],k[13]) CMPX(k[6],k[14]) CMPX(k[7],k[15])
    CMPX(k[0],k[4]) CMPX(k[1],k[5]) CMPX(k[2],k[6])  CMPX(k[3],k[7])
    CMPX(k[8],k[12]) CMPX(k[9],k[13]) CMPX(k[10],k[14]) CMPX(k[11],k[15])
    CMPX(k[0],k[2]) CMPX(k[1],k[3]) CMPX(k[4],k[6])  CMPX(k[5],k[7])
    CMPX(k[8],k[10]) CMPX(k[9],k[11]) CMPX(k[12],k[14]) CMPX(k[13],k[15])
    CMPX(k[0],k[1]) CMPX(k[2],k[3]) CMPX(k[4],k[5])  CMPX(k[6],k[7])
    CMPX(k[8],k[9]) CMPX(k[10],k[11]) CMPX(k[12],k[13]) CMPX(k[14],k[15])
}

// one butterfly merge step: my sorted-16 vs partner's sorted-16 -> top-16 of union, sorted
template<int OFF>
__device__ __forceinline__ void merge16(unsigned k[CAND]) {
    unsigned pk[CAND];
#pragma unroll
    for (int j = 0; j < CAND; ++j) pk[j] = shx<OFF>(k[j]);
#pragma unroll
    for (int j = 0; j < CAND; ++j) {
        unsigned b2_ = pk[CAND - 1 - j];
        k[j] = (k[j] < b2_) ? k[j] : b2_;
    }
    clean16(k);
}

// R14: per-lane sorted-8 -> 32-LANE-GROUP top-16 via xor butterfly.
// Same chain as the proven 64-lane wave16 minus the xor-32 level: build16
// (xor1) covers lane pairs, merge<2> 4-lane, merge<7> (half-mirror) 8-lane,
// merge<15> (mirror) 16-lane, merge<16> 32-lane.
__device__ __forceinline__ void group16(const unsigned (&run)[8], unsigned (&k16)[CAND]) {
    unsigned p8[8];
#pragma unroll
    for (int jj = 0; jj < 8; ++jj) p8[jj] = shx<1>(run[jj]);
#pragma unroll
    for (int jj = 0; jj < 8; ++jj) { k16[jj] = run[jj]; k16[8 + jj] = p8[7 - jj]; }
    clean16(k16);
    merge16<2>(k16);
    merge16<7>(k16);
    merge16<15>(k16);
    merge16<16>(k16);
}

// R7 prep + R10 xt16 mirror: single pass over x emits hi/lo bf16 MFMA
// operands, the coalesced out-first-half copy, the xx reduction, AND a
// point-major fp16 mirror xt16[b][n][c] for the epilogue gather.
__global__ __launch_bounds__(256) void prep_bswz(const float* __restrict__ x,
                                                 u16* __restrict__ bswz,
                                                 float* __restrict__ xx,
                                                 u16* __restrict__ xt16,
                                                 float* __restrict__ out) {
    __shared__ float red[256];
    const int t = blockIdx.x * 256 + threadIdx.x;   // [0, B*NTILE*4*64)
    const int lane = t & 63;
    const int ks   = (t >> 6) & 3;
    const int tt   = (t >> 8) & (NTILE - 1);
    const int b    = t >> 14;
    const int n    = tt * 32 + (lane & 31);
    const int c0   = ks * 16 + (lane >> 5) * 8;
    const float* src = x + b * (CC * NN) + n;
    unsigned oh[8], ol[8], oq[8];
    float ss = 0.f;
    float* ob = out + (size_t)b * (CC * 2 * NN) + n;
#pragma unroll
    for (int i = 0; i < 8; ++i) {
        const float v = src[(c0 + i) * NN];           // 32 consecutive lanes -> 128B contiguous
        ss = fmaf(v, v, ss);
        unsigned u = __float_as_uint(v);
        unsigned hb = (u + 0x7FFFu + ((u >> 16) & 1u)) >> 16;       // RNE -> bf16 (hi)
        const float vl = v - __uint_as_float(hb << 16);             // exact residual
        unsigned u2 = __float_as_uint(vl);
        ol[i] = (u2 + 0x7FFFu + ((u2 >> 16) & 1u)) >> 16;           // RNE -> bf16 (lo)
        oh[i] = hb;
        oq[i] = f2h(v);                                              // fp16 mirror
        ob[(size_t)(c0 + i) * (2 * NN)] = v;          // out first half: coalesced copy of x
    }
    const size_t uh = (((size_t)b * NTILE + tt) * 8 + ks) * 64 + lane;       // p=0
    const size_t ul = (((size_t)b * NTILE + tt) * 8 + 4 + ks) * 64 + lane;   // p=1
    *(uint4*)(bswz + uh * 8) = make_uint4(oh[0] | (oh[1] << 16), oh[2] | (oh[3] << 16),
                                          oh[4] | (oh[5] << 16), oh[6] | (oh[7] << 16));
    *(uint4*)(bswz + ul * 8) = make_uint4(ol[0] | (ol[1] << 16), ol[2] | (ol[3] << 16),
                                          ol[4] | (ol[5] << 16), ol[6] | (ol[7] << 16));
    // xt16[b][n][c0..c0+7]: 16B per thread, point-major
    *(uint4*)(xt16 + ((size_t)b * NN + n) * CC + c0) =
        make_uint4(oq[0] | (oq[1] << 16), oq[2] | (oq[3] << 16),
                   oq[4] | (oq[5] << 16), oq[6] | (oq[7] << 16));
    // xx: point pt = lane&31 has 8 contributors at threadIdx = pt + 32*j, j=0..7
    red[threadIdx.x] = ss;
    __syncthreads();
    if (threadIdx.x < 32) {
        float s = red[threadIdx.x];
#pragma unroll
        for (int j2 = 1; j2 < 8; ++j2) s += red[threadIdx.x + j2 * 32];
        xx[b * NN + tt * 32 + threadIdx.x] = s;
    }
}

// R14: half-wave item split + <=64-unified-reg occupancy class.
// m69 quantum: waves/SIMD halves at total regs {64,128,256}; R12's 72 regs
// -> 4 waves/SIMD class (2 blocks/CU); R13 proved 3+ blocks run when total
// <= 64, but got there by spilling. Here the structure itself fits:
//  - lanes 0-31 own item0's select, 32-63 own item1's: ONE run[8] (was 2),
//    ONE sort8+merge per chunk (was 2 sel_q), ONE group16 (4 merge levels,
//    was 2 x 5), ONE finish with 2 channels/lane (was 2) -> ~10% VALU cut.
//  - B loads inside chunk with single bv[4] (peak in-flight 16 regs);
//    intra-wave load cover no longer needed — cover comes from co-resident
//    blocks (4/CU at 37.4KB LDS each).
// Phase A math, prep layout, epilogue, gap test: R12-verbatim.
__global__ __launch_bounds__(NT, 8) void knn_upsample(const float* __restrict__ x,
                                                      const float* __restrict__ xxg,
                                                      const u16* __restrict__ bswz,
                                                      const u16* __restrict__ xt16,
                                                      float* __restrict__ out) {
    __shared__ unsigned ck[2][2 * QB][256];   // 32 KB: [buf][query 0-15][src_w*32+col]
    __shared__ float lds_mean[64][18];        // [channel][query-in-block], pad 18 -> 2-way alias

    const int tid  = threadIdx.x;
    const int w    = tid >> 6;                 // wave id = query row within item
    const int lane = tid & 63;
    const int grp  = lane >> 5;                // 0 = item0 half, 1 = item1 half
    const int blk  = blockIdx.x;

    // XCD-aware batch affinity (R13): 2048 blocks round-robin to 8 XCDs;
    // pin XCD x to batches {2x, 2x+1}.
    const int xcd = blk & 7;
    const int pj  = blk >> 3;                  // [0, 256)
    const int b   = 2 * xcd + (pj >> 7);       // batch
    const int jq  = pj & 127;                  // 16-query pair-group within batch
    const int n0a = jq << 4;                   // item0 query group
    const int n0b = n0a + 8;                   // item1 query group
    const float* xb = x + b * (CC * NN);
    const _Float16* xtb = (const _Float16*)(xt16 + (size_t)b * NN * CC);

    const int col = lane & 31;                 // MFMA row/col index
    const int h   = lane >> 5;                 // k-half (channels 8h..8h+7 of each k-step)
    const int mbase = w * MPW;                 // 256 m-points per wave (tiles w*8 .. w*8+7)
    const u16* bp = bswz + (((size_t)b * NTILE + w * TPW) * 8) * 64 * 8 + lane * 8;
    const float* xxp = xxg + (b << 11);

    // A frags: col 0-7 item0-hi(q=col), 8-15 item0-lo, 16-23 item1-hi, 24-31 item1-lo
    short8 afrag[4];
    {
        const int qi = col & 7;
        const int p  = (col >> 3) & 1;         // hi/lo
        const int nq = n0a + (col >> 4) * 8 + qi;
        const u16* ap = bswz + ((((size_t)b * NTILE + (nq >> 5)) * 8 + p * 4) * 64
                                + h * 32 + (nq & 31)) * 8;
#pragma unroll
        for (int ks = 0; ks < 4; ++ks)
            afrag[ks] = *(const short8*)(ap + (size_t)ks * 64 * 8);
    }

#define LOADB(t8_, slot_) (*(const short8*)(bp + ((size_t)((t8_) * 8 + (slot_)) * 64) * 8))

    unsigned run[8];                           // running per-lane top-8 (this half's item)
#pragma unroll
    for (int i = 0; i < 8; ++i) run[i] = 0xFFFFFFFFu;

    // one chunk of phase A: single bv buffer, single accumulator (R12 math)
    auto do_chunk = [&](int t8) {
        f32x16 acc;                            // q·(m_hi+m_lo), both items
#pragma unroll
        for (int i2 = 0; i2 < 16; ++i2) acc[i2] = 0.f;
        short8 bv[4];
#pragma unroll
        for (int ks = 0; ks < 4; ++ks) bv[ks] = LOADB(t8, ks);           // hi
#pragma unroll
        for (int ks = 0; ks < 4; ++ks)
            acc = __builtin_amdgcn_mfma_f32_32x32x16_bf16(afrag[ks], bv[ks], acc, 0, 0, 0);
#pragma unroll
        for (int ks = 0; ks < 4; ++ks) bv[ks] = LOADB(t8, 4 + ks);       // lo
#pragma unroll
        for (int ks = 0; ks < 4; ++ks)
            acc = __builtin_amdgcn_mfma_f32_32x32x16_bf16(afrag[ks], bv[ks], acc, 0, 0, 0);
        const int m = mbase + t8 * 32 + col;
        const float xxm = xxp[m];
        const int buf = t8 & 1;
        const int slot = w * 32 + col;
#pragma unroll
        for (int r = 0; r < 4; ++r) {
            const int q = 4 * h + r;           // lane half h owns query rows 4h..4h+3
            const float I0 = acc[r] + acc[r + 4];            // item0: hi-row + lo-row
            const float r0 = fmaf(-2.f, I0, xxm);
            const unsigned u0 = ordflip(r0);
            ck[buf][q][slot] = (m == n0a + q) ? 0xFFFFFFFFu : ((u0 & 0xFFFFF800u) | (unsigned)m);
            const float I1 = acc[r + 8] + acc[r + 12];       // item1
            const float r1 = fmaf(-2.f, I1, xxm);
            const unsigned u1 = ordflip(r1);
            ck[buf][8 + q][slot] = (m == n0b + q) ? 0xFFFFFFFFu : ((u1 & 0xFFFFF800u) | (unsigned)m);
        }
    };

    // R14 select: 8 keys of this half's item -> sort8 -> top-8 of (run8 ∪ 8).
    // Lanes 0-31 read rows [w], lanes 32-63 rows [8+w]; stride-4-word reads,
    // lane l and l+32 share a bank (2-way alias = free, m136).
    auto sel8 = [&](int pb) {
        const unsigned* row = &ck[pb][grp * 8 + w][0];
        const uint4 ka = *(const uint4*)(row + 4 * col);
        const uint4 kb = *(const uint4*)(row + 128 + 4 * col);
        unsigned s0 = ka.x, s1 = ka.y, s2 = ka.z, s3 = ka.w;
        unsigned t0 = kb.x, t1 = kb.y, t2 = kb.z, t3 = kb.w;
        CMPX(s0, s1) CMPX(s2, s3) CMPX(s0, s2) CMPX(s1, s3) CMPX(s1, s2)   // sort4 asc
        CMPX(t0, t1) CMPX(t2, t3) CMPX(t0, t2) CMPX(t1, t3) CMPX(t1, t2)   // sort4 asc
        // bitonic 8-seq s0..s3 ++ t3..t0 -> clean8 -> sorted asc u0..u7
        unsigned u0 = s0, u1 = s1, u2 = s2, u3 = s3, u4 = t3, u5 = t2, u6 = t1, u7 = t0;
        CMPX(u0, u4) CMPX(u1, u5) CMPX(u2, u6) CMPX(u3, u7)
        CMPX(u0, u2) CMPX(u1, u3) CMPX(u4, u6) CMPX(u5, u7)
        CMPX(u0, u1) CMPX(u2, u3) CMPX(u4, u5) CMPX(u6, u7)
        // discard-merge: top-8 of (run ∪ u) -> bitonic -> clean8
        run[0] = run[0] < u7 ? run[0] : u7;
        run[1] = run[1] < u6 ? run[1] : u6;
        run[2] = run[2] < u5 ? run[2] : u5;
        run[3] = run[3] < u4 ? run[3] : u4;
        run[4] = run[4] < u3 ? run[4] : u3;
        run[5] = run[5] < u2 ? run[5] : u2;
        run[6] = run[6] < u1 ? run[6] : u1;
        run[7] = run[7] < u0 ? run[7] : u0;
        CMPX(run[0], run[4]) CMPX(run[1], run[5]) CMPX(run[2], run[6]) CMPX(run[3], run[7])
        CMPX(run[0], run[2]) CMPX(run[1], run[3]) CMPX(run[4], run[6]) CMPX(run[5], run[7])
        CMPX(run[0], run[1]) CMPX(run[2], run[3]) CMPX(run[4], run[5]) CMPX(run[6], run[7])
    };

    // ---- chunk 0: phase A only ----
    do_chunk(0);
    __syncthreads();

    // ---- chunks 1..7: sel(c-1) -> phaseA(c) -> barrier ----
    for (int c = 1; c < TPW; ++c) {
        sel8((c - 1) & 1);
        do_chunk(c);
        __syncthreads();
    }
#undef LOADB

    // ---- final select chunk (tile 7, buf 1) ----
    sel8(1);

    // ---- group butterfly + gap test + mean (once per wave; 2 channels/lane) ----
    unsigned k16[CAND];
    group16(run, k16);
    {
        const int src = lane & 32;             // group leader
        int i16[CAND];
#pragma unroll
        for (int jj = 0; jj < CAND; ++jj) i16[jj] = __shfl((int)(k16[jj] & 0x7FFu), src, 64);

        const float r7 = unflip(k16[7]), r8 = unflip(k16[8]);
        const float eps = fmaxf(fabsf(r7), fabsf(r8)) * 0.0009765625f + 2e-3f;  // R5-proven
        const int ch0 = col, ch1 = col + 32;   // this lane's two channels
        const int nq  = n0a + grp * 8 + w;     // this half's query
        const int qq  = grp * 8 + w;
        float s0 = 0.f, s1 = 0.f;
        if (r8 - r7 > eps) {
            // fast path: point-major fp16 mirror; ch0/ch1 hit the same 128B line
#pragma unroll
            for (int jj = 0; jj < KK; ++jj) {
                const _Float16* pt = xtb + (size_t)i16[jj] * CC;
                s0 += (float)pt[ch0];
                s1 += (float)pt[ch1];
            }
        } else {
            // slow path: exact fp64 rescore on ORIGINAL fp32 x, 32-lane reduce
            const double q0 = (double)xb[ch0 * NN + nq];
            const double q1 = (double)xb[ch1 * NN + nq];
            u64 ke[CAND];
#pragma unroll
            for (int jj = 0; jj < CAND; ++jj) {
                const float x0 = xb[ch0 * NN + i16[jj]];
                const float x1 = xb[ch1 * NN + i16[jj]];
                const double d0 = (double)x0 - q0, d1 = (double)x1 - q1;
                double part = d0 * d0 + d1 * d1;
                part += dppd<0xB1>(part);
                part += dppd<0x4E>(part);
                part += dppd<0x141>(part);
                part += dppd<0x140>(part);
                part += __shfl_xor(part, 16, 64);
                u64 eb = (u64)__double_as_longlong(part);  // uniform within group, >= 0
                ke[jj] = (eb & ~2047ull) | (u64)(unsigned)i16[jj];
            }
            int rank[CAND];
#pragma unroll
            for (int jj = 0; jj < CAND; ++jj) rank[jj] = 0;
#pragma unroll
            for (int jj = 0; jj < CAND; ++jj)
#pragma unroll
                for (int k2 = jj + 1; k2 < CAND; ++k2) {
                    const bool jw = ke[jj] < ke[k2];
                    rank[k2] += jw ? 1 : 0;
                    rank[jj] += jw ? 0 : 1;
                }
#pragma unroll
            for (int jj = 0; jj < CAND; ++jj) {
                if (rank[jj] < KK) {
                    s0 += xb[ch0 * NN + i16[jj]];   // L1-hot reloads
                    s1 += xb[ch1 * NN + i16[jj]];
                }
            }
        }
        lds_mean[ch0][qq] = s0 * 0.125f;
        lds_mean[ch1][qq] = s1 * 0.125f;
    }

    __syncthreads();                           // all 16 query means staged

    // coalesced flush: out[b][c][N + n0a + qq], 16 consecutive floats per channel.
    // thread -> (c = tid>>3, qq = (tid&7)*2): float2 per thread, 64B per channel row.
    {
        const int c  = tid >> 3;
        const int q2 = (tid & 7) << 1;
        float2 mv = *(const float2*)&lds_mean[c][q2];
        *(float2*)(out + (size_t)b * (CC * 2 * NN) + (size_t)c * (2 * NN) + NN + n0a + q2) = mv;
    }
}

extern "C" void kernel_launch(void* const* d_in, const int* in_sizes, int n_in,
                              void* d_out, int out_size, void* d_ws, size_t ws_size,
                              hipStream_t stream) {
    (void)in_sizes; (void)n_in; (void)ws_size; (void)out_size;
    const float* x = (const float*)d_in[0];
    float* xx = (float*)d_ws;                                        // 128 KB
    u16* bswz = (u16*)((char*)d_ws + (size_t)BB * NN * 4);           // 16 MB swizzled bf16 hi/lo
    u16* xt16 = bswz + (size_t)BB * NN * CC * 2;                     // 4 MB fp16 point-major
    float* out = (float*)d_out;
    prep_bswz<<<dim3(BB * NTILE * 4 * 64 / 256), dim3(256), 0, stream>>>(x, bswz, xx, xt16, out);
    knn_upsample<<<dim3(BB * NN / QB / 2), dim3(NT), 0, stream>>>(x, xx, bswz, xt16, out);
}

// Round 15
// 154.075 us; speedup vs baseline: 1.1509x; 1.1509x over previous
//
#include <hip/hip_runtime.h>
#include <math.h>

#define BB 16
#define CC 64
#define NN 2048
#define KK 8
#define CAND 16          // phase-1 candidates (exact top-8 subset; validated R3/R6/R7/R10-R17)
#define QB 8             // query rows per item (one per wave)
#define NT (QB * 64)     // 512 threads
#define MPW (NN / QB)    // 256 m-points per wave
#define TPW (MPW / 32)   // 8 col-tiles of 32 m-points per wave
#define NTILE (NN / 32)  // 64 m-tiles per batch

typedef unsigned long long u64;
typedef unsigned short u16;
typedef __attribute__((ext_vector_type(8)))  short short8;   // 8 bf16 = 4 VGPRs (MFMA A/B frag)
typedef __attribute__((ext_vector_type(16))) float f32x16;   // MFMA 32x32 C/D frag

// order-preserving fp32 -> u32 flip: ascending uint == ascending float
__device__ __forceinline__ unsigned ordflip(float f) {
    unsigned u = __float_as_uint(f);
    return u ^ ((u & 0x80000000u) ? 0xFFFFFFFFu : 0x80000000u);
}
// inverse (on the masked high bits): recover approximate r from a packed key
__device__ __forceinline__ float unflip(unsigned k) {
    unsigned u = k & 0xFFFFF800u;
    u ^= (u & 0x80000000u) ? 0x80000000u : 0xFFFFFFFFu;
    return __uint_as_float(u);
}

__device__ __forceinline__ u16 f2h(float v) {
    union { _Float16 h; u16 u; } c;
    c.h = (_Float16)v;                 // RNE fp32 -> fp16
    return c.u;
}

// ---- cross-lane helpers: DPP for offsets inside a 16-lane row, bpermute beyond ----
template<int C>
__device__ __forceinline__ unsigned dppu(unsigned v) {
    return (unsigned)__builtin_amdgcn_update_dpp(0, (int)v, C, 0xF, 0xF, true);
}
template<int OFF>
__device__ __forceinline__ unsigned shx(unsigned v) {
    if constexpr (OFF == 1)       return dppu<0xB1>(v);    // quad_perm xor 1
    else if constexpr (OFF == 2)  return dppu<0x4E>(v);    // quad_perm xor 2
    else if constexpr (OFF == 7)  return dppu<0x141>(v);   // row_half_mirror = xor 7
    else if constexpr (OFF == 15) return dppu<0x140>(v);   // row_mirror      = xor 15
    else return (unsigned)__shfl_xor((int)v, OFF, 64);
}
template<int C>
__device__ __forceinline__ double dppd(double v) {
    unsigned long long u = (unsigned long long)__double_as_longlong(v);
    int lo = __builtin_amdgcn_update_dpp(0, (int)(u & 0xffffffffull), C, 0xF, 0xF, true);
    int hi = __builtin_amdgcn_update_dpp(0, (int)(u >> 32),           C, 0xF, 0xF, true);
    return __longlong_as_double((long long)(((unsigned long long)(unsigned)hi << 32) | (unsigned)lo));
}

#define CMPX(a_, b_) { unsigned lo_ = (a_) < (b_) ? (a_) : (b_); \
                       unsigned hi_ = (a_) < (b_) ? (b_) : (a_); (a_) = lo_; (b_) = hi_; }

// ascending bitonic cleanup of a bitonic 16-sequence (j = 8,4,2,1)
__device__ __forceinline__ void clean16(unsigned k[CAND]) {
    CMPX(k[0],k[8]) CMPX(k[1],k[9]) CMPX(k[2],k[10]) CMPX(k[3],k[11])
    CMPX(k[4],k[12]) CMPX(k[5],k[13]) CMPX(k[6],k[14]) CMPX(k[7],k[15])
    CMPX(k[0],k[4]) CMPX(k[1],k[5]) CMPX(k[2],k[6])  CMPX(k[3],k[7])
    CMPX(k[8],k[12]) CMPX(k[9],k[13]) CMPX(k[10],k[14]) CMPX(k[11],k[15])
    CMPX(k[0],k[2]) CMPX(k[1],k[3]) CMPX(k[4],k[6])  CMPX(k[5],k[7])
    CMPX(k[8],k[10]) CMPX(k[9],k[11]) CMPX(k[12],k[14]) CMPX(k[13],k[15])
    CMPX(k[0],k[1]) CMPX(k[2],k[3]) CMPX(k[4],k[5])  CMPX(k[6],k[7])
    CMPX(k[8],k[9]) CMPX(k[10],k[11]) CMPX(k[12],k[13]) CMPX(k[14],k[15])
}

// one butterfly merge step: my sorted-16 vs partner's sorted-16 -> top-16 of union, sorted
template<int OFF>
__device__ __forceinline__ void merge16(unsigned k[CAND]) {
    unsigned pk[CAND];
#pragma unroll
    for (int j = 0; j < CAND; ++j) pk[j] = shx<OFF>(k[j]);
#pragma unroll
    for (int j = 0; j < CAND; ++j) {
        unsigned b2_ = pk[CAND - 1 - j];
        k[j] = (k[j] < b2_) ? k[j] : b2_;
    }
    clean16(k);
}

// R14-validated: per-lane sorted-8 -> 32-LANE-GROUP top-16 via xor butterfly
// (wave16 chain minus the xor-32 level).
__device__ __forceinline__ void group16(const unsigned (&run)[8], unsigned (&k16)[CAND]) {
    unsigned p8[8];
#pragma unroll
    for (int jj = 0; jj < 8; ++jj) p8[jj] = shx<1>(run[jj]);
#pragma unroll
    for (int jj = 0; jj < 8; ++jj) { k16[jj] = run[jj]; k16[8 + jj] = p8[7 - jj]; }
    clean16(k16);
    merge16<2>(k16);
    merge16<7>(k16);
    merge16<15>(k16);
    merge16<16>(k16);
}

// R7 prep + R10 xt16 mirror: single pass over x emits hi/lo bf16 MFMA
// operands, the coalesced out-first-half copy, the xx reduction, AND a
// point-major fp16 mirror xt16[b][n][c] for the epilogue gather.
__global__ __launch_bounds__(256) void prep_bswz(const float* __restrict__ x,
                                                 u16* __restrict__ bswz,
                                                 float* __restrict__ xx,
                                                 u16* __restrict__ xt16,
                                                 float* __restrict__ out) {
    __shared__ float red[256];
    const int t = blockIdx.x * 256 + threadIdx.x;   // [0, B*NTILE*4*64)
    const int lane = t & 63;
    const int ks   = (t >> 6) & 3;
    const int tt   = (t >> 8) & (NTILE - 1);
    const int b    = t >> 14;
    const int n    = tt * 32 + (lane & 31);
    const int c0   = ks * 16 + (lane >> 5) * 8;
    const float* src = x + b * (CC * NN) + n;
    unsigned oh[8], ol[8], oq[8];
    float ss = 0.f;
    float* ob = out + (size_t)b * (CC * 2 * NN) + n;
#pragma unroll
    for (int i = 0; i < 8; ++i) {
        const float v = src[(c0 + i) * NN];           // 32 consecutive lanes -> 128B contiguous
        ss = fmaf(v, v, ss);
        unsigned u = __float_as_uint(v);
        unsigned hb = (u + 0x7FFFu + ((u >> 16) & 1u)) >> 16;       // RNE -> bf16 (hi)
        const float vl = v - __uint_as_float(hb << 16);             // exact residual
        unsigned u2 = __float_as_uint(vl);
        ol[i] = (u2 + 0x7FFFu + ((u2 >> 16) & 1u)) >> 16;           // RNE -> bf16 (lo)
        oh[i] = hb;
        oq[i] = f2h(v);                                              // fp16 mirror
        ob[(size_t)(c0 + i) * (2 * NN)] = v;          // out first half: coalesced copy of x
    }
    const size_t uh = (((size_t)b * NTILE + tt) * 8 + ks) * 64 + lane;       // p=0
    const size_t ul = (((size_t)b * NTILE + tt) * 8 + 4 + ks) * 64 + lane;   // p=1
    *(uint4*)(bswz + uh * 8) = make_uint4(oh[0] | (oh[1] << 16), oh[2] | (oh[3] << 16),
                                          oh[4] | (oh[5] << 16), oh[6] | (oh[7] << 16));
    *(uint4*)(bswz + ul * 8) = make_uint4(ol[0] | (ol[1] << 16), ol[2] | (ol[3] << 16),
                                          ol[4] | (ol[5] << 16), ol[6] | (ol[7] << 16));
    // xt16[b][n][c0..c0+7]: 16B per thread, point-major
    *(uint4*)(xt16 + ((size_t)b * NN + n) * CC + c0) =
        make_uint4(oq[0] | (oq[1] << 16), oq[2] | (oq[3] << 16),
                   oq[4] | (oq[5] << 16), oq[6] | (oq[7] << 16));
    // xx: point pt = lane&31 has 8 contributors at threadIdx = pt + 32*j, j=0..7
    red[threadIdx.x] = ss;
    __syncthreads();
    if (threadIdx.x < 32) {
        float s = red[threadIdx.x];
#pragma unroll
        for (int j2 = 1; j2 < 8; ++j2) s += red[threadIdx.x + j2 * 32];
        xx[b * NN + tt * 32 + threadIdx.x] = s;
    }
}

// R15 = R12's proven shell (bounds=4, bh/bl up-front loads, single-acc MFMA,
// NO occupancy coercion — R11/R13/R14 proved every forced class-drop spills)
// + R14's functionally-validated half-wave select: lanes 0-31 own item0,
// 32-63 own item1. Per chunk ONE sort8+discard-merge (was 2 sel_q), ONE
// group16 (4 merge levels, was 2x5), ONE finish with 2 channels/lane
// (was 2) -> ~25% select-VALU cut on the measured-busiest pipe (63%).
__global__ __launch_bounds__(NT, 4) void knn_upsample(const float* __restrict__ x,
                                                      const float* __restrict__ xxg,
                                                      const u16* __restrict__ bswz,
                                                      const u16* __restrict__ xt16,
                                                      float* __restrict__ out) {
    __shared__ unsigned ck[2][2 * QB][256];   // 32 KB: [buf][query 0-15][src_w*32+col]
    __shared__ float lds_mean[64][18];        // [channel][query-in-block], pad 18 -> 2-way alias

    const int tid  = threadIdx.x;
    const int w    = tid >> 6;                 // wave id = query row within item
    const int lane = tid & 63;
    const int grp  = lane >> 5;                // 0 = item0 half, 1 = item1 half
    const int blk  = blockIdx.x;

    // XCD-aware batch affinity (R13): 2048 blocks round-robin to 8 XCDs;
    // pin XCD x to batches {2x, 2x+1}.
    const int xcd = blk & 7;
    const int pj  = blk >> 3;                  // [0, 256)
    const int b   = 2 * xcd + (pj >> 7);       // batch
    const int jq  = pj & 127;                  // 16-query pair-group within batch
    const int n0a = jq << 4;                   // item0 query group
    const int n0b = n0a + 8;                   // item1 query group
    const float* xb = x + b * (CC * NN);
    const _Float16* xtb = (const _Float16*)(xt16 + (size_t)b * NN * CC);

    const int col = lane & 31;                 // MFMA row/col index
    const int h   = lane >> 5;                 // k-half (channels 8h..8h+7 of each k-step)
    const int mbase = w * MPW;                 // 256 m-points per wave (tiles w*8 .. w*8+7)
    const u16* bp = bswz + (((size_t)b * NTILE + w * TPW) * 8) * 64 * 8 + lane * 8;
    const float* xxp = xxg + (b << 11);

    // A frags: col 0-7 item0-hi(q=col), 8-15 item0-lo, 16-23 item1-hi, 24-31 item1-lo
    short8 afrag[4];
    {
        const int qi = col & 7;
        const int p  = (col >> 3) & 1;         // hi/lo
        const int nq = n0a + (col >> 4) * 8 + qi;
        const u16* ap = bswz + ((((size_t)b * NTILE + (nq >> 5)) * 8 + p * 4) * 64
                                + h * 32 + (nq & 31)) * 8;
#pragma unroll
        for (int ks = 0; ks < 4; ++ks)
            afrag[ks] = *(const short8*)(ap + (size_t)ks * 64 * 8);
    }

#define LOADB(t8_, slot_) (*(const short8*)(bp + ((size_t)((t8_) * 8 + (slot_)) * 64) * 8))

    unsigned run[8];                           // running per-lane top-8 (this half's item)
#pragma unroll
    for (int i = 0; i < 8; ++i) run[i] = 0xFFFFFFFFu;

    // one chunk of phase A: loads already issued into bh/bl; ONE accumulator (R12)
    auto mfma_epi = [&](int t8, const short8 (&bh)[4], const short8 (&bl)[4]) {
        f32x16 acc;                            // q·(m_hi+m_lo), both items
#pragma unroll
        for (int i2 = 0; i2 < 16; ++i2) acc[i2] = 0.f;
#pragma unroll
        for (int ks = 0; ks < 4; ++ks)
            acc = __builtin_amdgcn_mfma_f32_32x32x16_bf16(afrag[ks], bh[ks], acc, 0, 0, 0);
#pragma unroll
        for (int ks = 0; ks < 4; ++ks)
            acc = __builtin_amdgcn_mfma_f32_32x32x16_bf16(afrag[ks], bl[ks], acc, 0, 0, 0);
        const int m = mbase + t8 * 32 + col;
        const float xxm = xxp[m];
        const int buf = t8 & 1;
        const int slot = w * 32 + col;
#pragma unroll
        for (int r = 0; r < 4; ++r) {
            const int q = 4 * h + r;           // lane half h owns query rows 4h..4h+3
            const float I0 = acc[r] + acc[r + 4];            // item0: hi-row + lo-row
            const float r0 = fmaf(-2.f, I0, xxm);
            const unsigned u0 = ordflip(r0);
            ck[buf][q][slot] = (m == n0a + q) ? 0xFFFFFFFFu : ((u0 & 0xFFFFF800u) | (unsigned)m);
            const float I1 = acc[r + 8] + acc[r + 12];       // item1
            const float r1 = fmaf(-2.f, I1, xxm);
            const unsigned u1 = ordflip(r1);
            ck[buf][8 + q][slot] = (m == n0b + q) ? 0xFFFFFFFFu : ((u1 & 0xFFFFF800u) | (unsigned)m);
        }
    };

    // R14-validated select: 8 keys of this half's item -> sort8 -> top-8 of (run ∪ 8)
    auto sel8 = [&](int pb) {
        const unsigned* row = &ck[pb][grp * 8 + w][0];
        const uint4 ka = *(const uint4*)(row + 4 * col);
        const uint4 kb = *(const uint4*)(row + 128 + 4 * col);
        unsigned s0 = ka.x, s1 = ka.y, s2 = ka.z, s3 = ka.w;
        unsigned t0 = kb.x, t1 = kb.y, t2 = kb.z, t3 = kb.w;
        CMPX(s0, s1) CMPX(s2, s3) CMPX(s0, s2) CMPX(s1, s3) CMPX(s1, s2)   // sort4 asc
        CMPX(t0, t1) CMPX(t2, t3) CMPX(t0, t2) CMPX(t1, t3) CMPX(t1, t2)   // sort4 asc
        // bitonic 8-seq s0..s3 ++ t3..t0 -> clean8 -> sorted asc u0..u7
        unsigned u0 = s0, u1 = s1, u2 = s2, u3 = s3, u4 = t3, u5 = t2, u6 = t1, u7 = t0;
        CMPX(u0, u4) CMPX(u1, u5) CMPX(u2, u6) CMPX(u3, u7)
        CMPX(u0, u2) CMPX(u1, u3) CMPX(u4, u6) CMPX(u5, u7)
        CMPX(u0, u1) CMPX(u2, u3) CMPX(u4, u5) CMPX(u6, u7)
        // discard-merge: top-8 of (run ∪ u) -> bitonic -> clean8
        run[0] = run[0] < u7 ? run[0] : u7;
        run[1] = run[1] < u6 ? run[1] : u6;
        run[2] = run[2] < u5 ? run[2] : u5;
        run[3] = run[3] < u4 ? run[3] : u4;
        run[4] = run[4] < u3 ? run[4] : u3;
        run[5] = run[5] < u2 ? run[5] : u2;
        run[6] = run[6] < u1 ? run[6] : u1;
        run[7] = run[7] < u0 ? run[7] : u0;
        CMPX(run[0], run[4]) CMPX(run[1], run[5]) CMPX(run[2], run[6]) CMPX(run[3], run[7])
        CMPX(run[0], run[2]) CMPX(run[1], run[3]) CMPX(run[4], run[6]) CMPX(run[5], run[7])
        CMPX(run[0], run[1]) CMPX(run[2], run[3]) CMPX(run[4], run[5]) CMPX(run[6], run[7])
    };

    // ---- chunk 0: phase A only ----
    {
        short8 bh[4], bl[4];
#pragma unroll
        for (int ks = 0; ks < 4; ++ks) { bh[ks] = LOADB(0, ks); bl[ks] = LOADB(0, 4 + ks); }
        mfma_epi(0, bh, bl);
    }
    __syncthreads();

    // ---- chunks 1..7: loads(c) -> sel8(c-1) -> mfma_epi(c) -> barrier ----
    for (int c = 1; c < TPW; ++c) {
        short8 bh[4], bl[4];
#pragma unroll
        for (int ks = 0; ks < 4; ++ks) { bh[ks] = LOADB(c, ks); bl[ks] = LOADB(c, 4 + ks); }
        sel8((c - 1) & 1);
        mfma_epi(c, bh, bl);
        __syncthreads();
    }
#undef LOADB

    // ---- final select chunk (tile 7, buf 1) ----
    sel8(1);

    // ---- group butterfly + gap test + mean (once per wave; 2 channels/lane) ----
    unsigned k16[CAND];
    group16(run, k16);
    {
        const int src = lane & 32;             // group leader
        int i16[CAND];
#pragma unroll
        for (int jj = 0; jj < CAND; ++jj) i16[jj] = __shfl((int)(k16[jj] & 0x7FFu), src, 64);

        const float r7 = unflip(k16[7]), r8 = unflip(k16[8]);
        const float eps = fmaxf(fabsf(r7), fabsf(r8)) * 0.0009765625f + 2e-3f;  // R5-proven
        const int ch0 = col, ch1 = col + 32;   // this lane's two channels
        const int nq  = n0a + grp * 8 + w;     // this half's query
        const int qq  = grp * 8 + w;
        float s0 = 0.f, s1 = 0.f;
        if (r8 - r7 > eps) {
            // fast path: point-major fp16 mirror; ch0/ch1 hit the same 128B line
#pragma unroll
            for (int jj = 0; jj < KK; ++jj) {
                const _Float16* pt = xtb + (size_t)i16[jj] * CC;
                s0 += (float)pt[ch0];
                s1 += (float)pt[ch1];
            }
        } else {
            // slow path: exact fp64 rescore on ORIGINAL fp32 x, 32-lane reduce
            const double q0 = (double)xb[ch0 * NN + nq];
            const double q1 = (double)xb[ch1 * NN + nq];
            u64 ke[CAND];
#pragma unroll
            for (int jj = 0; jj < CAND; ++jj) {
                const float x0 = xb[ch0 * NN + i16[jj]];
                const float x1 = xb[ch1 * NN + i16[jj]];
                const double d0 = (double)x0 - q0, d1 = (double)x1 - q1;
                double part = d0 * d0 + d1 * d1;
                part += dppd<0xB1>(part);
                part += dppd<0x4E>(part);
                part += dppd<0x141>(part);
                part += dppd<0x140>(part);
                part += __shfl_xor(part, 16, 64);
                u64 eb = (u64)__double_as_longlong(part);  // uniform within group, >= 0
                ke[jj] = (eb & ~2047ull) | (u64)(unsigned)i16[jj];
            }
            int rank[CAND];
#pragma unroll
            for (int jj = 0; jj < CAND; ++jj) rank[jj] = 0;
#pragma unroll
            for (int jj = 0; jj < CAND; ++jj)
#pragma unroll
                for (int k2 = jj + 1; k2 < CAND; ++k2) {
                    const bool jw = ke[jj] < ke[k2];
                    rank[k2] += jw ? 1 : 0;
                    rank[jj] += jw ? 0 : 1;
                }
#pragma unroll
            for (int jj = 0; jj < CAND; ++jj) {
                if (rank[jj] < KK) {
                    s0 += xb[ch0 * NN + i16[jj]];   // L1-hot reloads
                    s1 += xb[ch1 * NN + i16[jj]];
                }
            }
        }
        lds_mean[ch0][qq] = s0 * 0.125f;
        lds_mean[ch1][qq] = s1 * 0.125f;
    }

    __syncthreads();                           // all 16 query means staged

    // coalesced flush: out[b][c][N + n0a + qq], 16 consecutive floats per channel.
    // thread -> (c = tid>>3, qq = (tid&7)*2): float2 per thread, 64B per channel row.
    {
        const int c  = tid >> 3;
        const int q2 = (tid & 7) << 1;
        float2 mv = *(const float2*)&lds_mean[c][q2];
        *(float2*)(out + (size_t)b * (CC * 2 * NN) + (size_t)c * (2 * NN) + NN + n0a + q2) = mv;
    }
}

extern "C" void kernel_launch(void* const* d_in, const int* in_sizes, int n_in,
                              void* d_out, int out_size, void* d_ws, size_t ws_size,
                              hipStream_t stream) {
    (void)in_sizes; (void)n_in; (void)ws_size; (void)out_size;
    const float* x = (const float*)d_in[0];
    float* xx = (float*)d_ws;                                        // 128 KB
    u16* bswz = (u16*)((char*)d_ws + (size_t)BB * NN * 4);           // 8 MB swizzled bf16 hi/lo
    u16* xt16 = bswz + (size_t)BB * NN * CC * 2;                     // 2 MB fp16 point-major
    float* out = (float*)d_out;
    prep_bswz<<<dim3(BB * NTILE * 4 * 64 / 256), dim3(256), 0, stream>>>(x, bswz, xx, xt16, out);
    knn_upsample<<<dim3(BB * NN / QB / 2), dim3(NT), 0, stream>>>(x, xx, bswz, xt16, out);
}